// Round 1
// baseline (413.866 us; speedup 1.0000x reference)
//
#include <hip/hip_runtime.h>
#include <stdint.h>

#define NHEAD  16
#define SEQ    2048
#define DMODEL 1024
#define BATCH  4

typedef __attribute__((ext_vector_type(4))) float f32x4;
typedef __attribute__((ext_vector_type(8))) __bf16 bf16x8;
typedef __attribute__((ext_vector_type(8))) unsigned short u16x8;

__device__ __forceinline__ unsigned short f2bf(float f) {
    unsigned int u = __builtin_bit_cast(unsigned int, f);
    u += 0x7FFFu + ((u >> 16) & 1u);   // RNE
    return (unsigned short)(u >> 16);
}

// async global->LDS, 16B per lane. LDS dest must be wave-uniform base + lane*16.
__device__ __forceinline__ void gload_lds16(const void* g, void* l) {
    __builtin_amdgcn_global_load_lds(
        (const __attribute__((address_space(1))) unsigned int*)(uintptr_t)g,
        (__attribute__((address_space(3))) unsigned int*)(uintptr_t)l,
        16, 0, 0);
}

__device__ __forceinline__ bf16x8 lds_frag(const unsigned short* p) {
    return __builtin_bit_cast(bf16x8, *(const u16x8*)p);
}

// ---------------- fp32 -> bf16 conversion ----------------
__global__ __launch_bounds__(256) void cvt_f32_bf16(const float* __restrict__ src,
                                                    unsigned short* __restrict__ dst, int n4) {
    int i = blockIdx.x * 256 + threadIdx.x;
    if (i < n4) {
        float4 v = ((const float4*)src)[i];
        ushort4 o;
        o.x = f2bf(v.x); o.y = f2bf(v.y); o.z = f2bf(v.z); o.w = f2bf(v.w);
        ((ushort4*)dst)[i] = o;
    }
}

// ---------------- 128x128 GEMM: C = A(MxK) * W(NxK)^T ----------------
// MODE 0: RoPE epilogue, write bf16 to (b,h,s,dk)
// MODE 1: write bf16 to (b,h,dk,s)   (transposed V)
// MODE 2: write fp32 to (m,n) d_out
template <int MODE>
__global__ __launch_bounds__(256) void gemm128(const unsigned short* __restrict__ A,
                                               const unsigned short* __restrict__ W,
                                               void* __restrict__ dst) {
    __shared__ __align__(16) unsigned short As[128 * 64];
    __shared__ __align__(16) unsigned short Bs[128 * 64];

    const int tid  = threadIdx.x;
    const int lane = tid & 63;
    const int wid  = tid >> 6;
    const int wm = wid >> 1, wn = wid & 1;
    const int l15 = lane & 15, lg = lane >> 4;

    const int tn = blockIdx.x & 7;   // N/128 = 8
    const int tm = blockIdx.x >> 3;
    const int m0 = tm * 128, n0 = tn * 128;

    f32x4 acc[4][4];
#pragma unroll
    for (int i = 0; i < 4; i++)
#pragma unroll
        for (int j = 0; j < 4; j++) acc[i][j] = f32x4{0.f, 0.f, 0.f, 0.f};

    for (int kk = 0; kk < 1024; kk += 64) {
#pragma unroll
        for (int is = 0; is < 4; ++is) {
            int e = (is * 256 + tid) * 8;   // element within 128x64 tile
            int row = e >> 6, col = e & 63;
            gload_lds16(A + (size_t)(m0 + row) * 1024 + kk + col, &As[e]);
            gload_lds16(W + (size_t)(n0 + row) * 1024 + kk + col, &Bs[e]);
        }
        __syncthreads();   // drains vmcnt for global_load_lds
#pragma unroll
        for (int ks = 0; ks < 2; ++ks) {
            bf16x8 a[4], b[4];
#pragma unroll
            for (int f = 0; f < 4; f++) {
                a[f] = lds_frag(&As[(wm * 64 + f * 16 + l15) * 64 + ks * 32 + lg * 8]);
                b[f] = lds_frag(&Bs[(wn * 64 + f * 16 + l15) * 64 + ks * 32 + lg * 8]);
            }
#pragma unroll
            for (int i = 0; i < 4; i++)
#pragma unroll
                for (int j = 0; j < 4; j++)
                    acc[i][j] = __builtin_amdgcn_mfma_f32_16x16x32_bf16(a[i], b[j], acc[i][j], 0, 0, 0);
        }
        __syncthreads();
    }

    // epilogue: lane holds C[m][n], m = m0+wm*64+i*16+lg*4+r, n = n0+wn*64+j*16+l15
    if (MODE == 2) {
        float* out = (float*)dst;
#pragma unroll
        for (int i = 0; i < 4; i++)
#pragma unroll
            for (int r = 0; r < 4; r++) {
                int m = m0 + wm * 64 + i * 16 + lg * 4 + r;
                float* orow = out + (size_t)m * 1024 + n0 + wn * 64 + l15;
#pragma unroll
                for (int j = 0; j < 4; j++) orow[j * 16] = acc[i][j][r];
            }
    } else if (MODE == 1) {
        unsigned short* out = (unsigned short*)dst;
#pragma unroll
        for (int i = 0; i < 4; i++)
#pragma unroll
            for (int r = 0; r < 4; r++) {
                int m = m0 + wm * 64 + i * 16 + lg * 4 + r;
                int b = m >> 11, s = m & 2047;
#pragma unroll
                for (int j = 0; j < 4; j++) {
                    int n = n0 + wn * 64 + j * 16 + l15;
                    int h = n >> 6, dk = n & 63;
                    out[((size_t)(b * NHEAD + h) * 64 + dk) * SEQ + s] = f2bf(acc[i][j][r]);
                }
            }
    } else {
        unsigned short* out = (unsigned short*)dst;
        const float L2T = 13.287712379549449f;   // log2(10000)
        float invf[4];
#pragma unroll
        for (int j = 0; j < 4; j++) {
            int idx = j * 16 + l15;          // n % 64
            int t = idx >> 1;
            invf[j] = exp2f(-((float)(2 * t) * (1.0f / 64.0f)) * L2T);
        }
        const int par = l15 & 1;
#pragma unroll
        for (int i = 0; i < 4; i++)
#pragma unroll
            for (int r = 0; r < 4; r++) {
                int m = m0 + wm * 64 + i * 16 + lg * 4 + r;
                int b = m >> 11, s = m & 2047;
                float fs = (float)s;
#pragma unroll
                for (int j = 0; j < 4; j++) {
                    float v = acc[i][j][r];
                    float other = __shfl_xor(v, 1);
                    float sn, cs;
                    __sincosf(fs * invf[j], &sn, &cs);
                    float y = par ? fmaf(v, cs, other * sn) : fmaf(v, cs, -other * sn);
                    int n = n0 + wn * 64 + j * 16 + l15;
                    int h = n >> 6, dk = n & 63;
                    out[((size_t)(b * NHEAD + h) * SEQ + s) * 64 + dk] = f2bf(y);
                }
            }
    }
}

// ---------------- causal flash attention ----------------
// grid: (b*h)*32 q-blocks of 64 rows. Q,K in (bh, s, dk); V in (bh, dk, s). Out (b,s,dmodel) bf16.
__global__ __launch_bounds__(256) void flash_attn(const unsigned short* __restrict__ Qw,
                                                  const unsigned short* __restrict__ Kw,
                                                  const unsigned short* __restrict__ Vw,
                                                  unsigned short* __restrict__ Ow) {
    __shared__ __align__(16) unsigned short Qs[64 * 64];
    __shared__ __align__(16) unsigned short Ks[64 * 64];
    __shared__ __align__(16) unsigned short Vs[64 * 64];   // [dk][kv]
    __shared__ __align__(16) unsigned short Ps[64 * 72];   // padded rows

    const int tid  = threadIdx.x;
    const int lane = tid & 63;
    const int w    = tid >> 6;
    const int l15 = lane & 15, lg = lane >> 4;

    const int qb = blockIdx.x & 31;
    const int bh = blockIdx.x >> 5;

    const unsigned short* Qbase = Qw + (size_t)bh * (SEQ * 64) + qb * (64 * 64);
    const unsigned short* Kbh   = Kw + (size_t)bh * (SEQ * 64);
    const unsigned short* Vbh   = Vw + (size_t)bh * (64 * SEQ);

#pragma unroll
    for (int is = 0; is < 2; ++is) {
        int e = (is * 256 + tid) * 8;
        gload_lds16(Qbase + e, &Qs[e]);
    }

    f32x4 oacc[4];
#pragma unroll
    for (int f = 0; f < 4; f++) oacc[f] = f32x4{0.f, 0.f, 0.f, 0.f};
    float mrun[4], lrun[4];
#pragma unroll
    for (int r = 0; r < 4; r++) { mrun[r] = -3.0e38f; lrun[r] = 0.f; }

    const int qrow0 = w * 16;

    for (int kt = 0; kt <= qb; ++kt) {
#pragma unroll
        for (int is = 0; is < 2; ++is) {
            int e = (is * 256 + tid) * 8;
            gload_lds16(Kbh + (size_t)kt * (64 * 64) + e, &Ks[e]);
            int dk = e >> 6, so = e & 63;
            gload_lds16(Vbh + (size_t)dk * SEQ + kt * 64 + so, &Vs[e]);
        }
        __syncthreads();

        // S = Q K^T
        f32x4 sacc[4];
#pragma unroll
        for (int f = 0; f < 4; f++) sacc[f] = f32x4{0.f, 0.f, 0.f, 0.f};
#pragma unroll
        for (int ks = 0; ks < 2; ++ks) {
            bf16x8 aq = lds_frag(&Qs[(qrow0 + l15) * 64 + ks * 32 + lg * 8]);
#pragma unroll
            for (int f = 0; f < 4; f++) {
                bf16x8 bk = lds_frag(&Ks[(f * 16 + l15) * 64 + ks * 32 + lg * 8]);
                sacc[f] = __builtin_amdgcn_mfma_f32_16x16x32_bf16(aq, bk, sacc[f], 0, 0, 0);
            }
        }

        // scale + causal mask (diag tile only)
        if (kt == qb) {
#pragma unroll
            for (int f = 0; f < 4; f++) {
                int kvl = f * 16 + l15;
#pragma unroll
                for (int r = 0; r < 4; r++) {
                    int ql = qrow0 + lg * 4 + r;
                    float v = sacc[f][r] * 0.125f;
                    sacc[f][r] = (kvl > ql) ? -3.0e38f : v;
                }
            }
        } else {
#pragma unroll
            for (int f = 0; f < 4; f++)
#pragma unroll
                for (int r = 0; r < 4; r++) sacc[f][r] *= 0.125f;
        }

        // online softmax; rows of reg r live in fixed 16-lane group -> butterfly 1/2/4/8
        float sc[4];
#pragma unroll
        for (int r = 0; r < 4; r++) {
            float tmax = fmaxf(fmaxf(sacc[0][r], sacc[1][r]), fmaxf(sacc[2][r], sacc[3][r]));
            tmax = fmaxf(tmax, __shfl_xor(tmax, 1));
            tmax = fmaxf(tmax, __shfl_xor(tmax, 2));
            tmax = fmaxf(tmax, __shfl_xor(tmax, 4));
            tmax = fmaxf(tmax, __shfl_xor(tmax, 8));
            float mnew = fmaxf(mrun[r], tmax);
            sc[r] = __expf(mrun[r] - mnew);
            mrun[r] = mnew;
            float lsum = 0.f;
#pragma unroll
            for (int f = 0; f < 4; f++) {
                float e = __expf(sacc[f][r] - mnew);
                sacc[f][r] = e;
                lsum += e;
            }
            lsum += __shfl_xor(lsum, 1);
            lsum += __shfl_xor(lsum, 2);
            lsum += __shfl_xor(lsum, 4);
            lsum += __shfl_xor(lsum, 8);
            lrun[r] = lrun[r] * sc[r] + lsum;
        }
#pragma unroll
        for (int f = 0; f < 4; f++)
#pragma unroll
            for (int r = 0; r < 4; r++) oacc[f][r] *= sc[r];

        // P -> LDS (each wave writes/reads only its own 16 q-rows)
#pragma unroll
        for (int f = 0; f < 4; f++)
#pragma unroll
            for (int r = 0; r < 4; r++)
                Ps[(qrow0 + lg * 4 + r) * 72 + f * 16 + l15] = f2bf(sacc[f][r]);

        // O += P V
#pragma unroll
        for (int ks = 0; ks < 2; ++ks) {
            bf16x8 pa = lds_frag(&Ps[(qrow0 + l15) * 72 + ks * 32 + lg * 8]);
#pragma unroll
            for (int f = 0; f < 4; f++) {
                bf16x8 vb = lds_frag(&Vs[(f * 16 + l15) * 64 + ks * 32 + lg * 8]);
                oacc[f] = __builtin_amdgcn_mfma_f32_16x16x32_bf16(pa, vb, oacc[f], 0, 0, 0);
            }
        }
        __syncthreads();
    }

    const int b = bh >> 4, h = bh & 15;
#pragma unroll
    for (int r = 0; r < 4; r++) {
        int sg = qb * 64 + qrow0 + lg * 4 + r;
        float inv = 1.0f / lrun[r];
        unsigned short* orow = Ow + ((size_t)(b * SEQ + sg) * DMODEL) + h * 64 + l15;
#pragma unroll
        for (int f = 0; f < 4; f++) orow[f * 16] = f2bf(oacc[f][r] * inv);
    }
}

extern "C" void kernel_launch(void* const* d_in, const int* in_sizes, int n_in,
                              void* d_out, int out_size, void* d_ws, size_t ws_size,
                              hipStream_t stream) {
    const float* x  = (const float*)d_in[0];
    const float* wq = (const float*)d_in[1];
    const float* wk = (const float*)d_in[2];
    const float* wv = (const float*)d_in[3];
    const float* wo = (const float*)d_in[4];

    unsigned short* ws = (unsigned short*)d_ws;
    const size_t MEL = (size_t)8192 * 1024;   // 8M elements
    const size_t WEL = (size_t)1024 * 1024;   // 1M elements
    unsigned short* xb  = ws;
    unsigned short* wqb = xb + MEL;
    unsigned short* wkb = wqb + WEL;
    unsigned short* wvb = wkb + WEL;
    unsigned short* wob = wvb + WEL;
    unsigned short* qw  = wob + WEL;
    unsigned short* kw  = qw + MEL;
    unsigned short* vw  = kw + MEL;
    unsigned short* ow  = vw + MEL;
    // total: 44M ushort = 88 MB of d_ws

    cvt_f32_bf16<<<8192, 256, 0, stream>>>(x, xb, (int)(MEL / 4));
    cvt_f32_bf16<<<1024, 256, 0, stream>>>(wq, wqb, (int)(WEL / 4));
    cvt_f32_bf16<<<1024, 256, 0, stream>>>(wk, wkb, (int)(WEL / 4));
    cvt_f32_bf16<<<1024, 256, 0, stream>>>(wv, wvb, (int)(WEL / 4));
    cvt_f32_bf16<<<1024, 256, 0, stream>>>(wo, wob, (int)(WEL / 4));

    gemm128<0><<<512, 256, 0, stream>>>(xb, wqb, qw);   // Q + RoPE -> (b,h,s,dk)
    gemm128<0><<<512, 256, 0, stream>>>(xb, wkb, kw);   // K + RoPE -> (b,h,s,dk)
    gemm128<1><<<512, 256, 0, stream>>>(xb, wvb, vw);   // V -> (b,h,dk,s)

    flash_attn<<<4 * NHEAD * 32, 256, 0, stream>>>(qw, kw, vw, ow);

    gemm128<2><<<512, 256, 0, stream>>>(ow, wob, d_out);
}

// Round 2
// 263.197 us; speedup vs baseline: 1.5725x; 1.5725x over previous
//
#include <hip/hip_runtime.h>
#include <stdint.h>

#define NHEAD  16
#define SEQ    2048
#define DMODEL 1024
#define BATCH  4

typedef __attribute__((ext_vector_type(4))) float f32x4;
typedef __attribute__((ext_vector_type(8))) __bf16 bf16x8;
typedef __attribute__((ext_vector_type(8))) unsigned short u16x8;

__device__ __forceinline__ unsigned short f2bf(float f) {
    unsigned int u = __builtin_bit_cast(unsigned int, f);
    u += 0x7FFFu + ((u >> 16) & 1u);   // RNE
    return (unsigned short)(u >> 16);
}

// async global->LDS, 16B per lane. LDS dest must be wave-uniform base + lane*16.
__device__ __forceinline__ void gload_lds16(const void* g, void* l) {
    __builtin_amdgcn_global_load_lds(
        (const __attribute__((address_space(1))) unsigned int*)(uintptr_t)g,
        (__attribute__((address_space(3))) unsigned int*)(uintptr_t)l,
        16, 0, 0);
}

__device__ __forceinline__ bf16x8 lds_frag(const unsigned short* p) {
    return __builtin_bit_cast(bf16x8, *(const u16x8*)p);
}

// ---------------- fp32 -> bf16 conversion ----------------
__global__ __launch_bounds__(256) void cvt_f32_bf16(const float* __restrict__ src,
                                                    unsigned short* __restrict__ dst, int n4) {
    int i = blockIdx.x * 256 + threadIdx.x;
    if (i < n4) {
        float4 v = ((const float4*)src)[i];
        ushort4 o;
        o.x = f2bf(v.x); o.y = f2bf(v.y); o.z = f2bf(v.z); o.w = f2bf(v.w);
        ((ushort4*)dst)[i] = o;
    }
}

// fused conversion of the 4 weight matrices (1M elements each)
__global__ __launch_bounds__(256) void cvt_weights(const float* __restrict__ w0,
                                                   const float* __restrict__ w1,
                                                   const float* __restrict__ w2,
                                                   const float* __restrict__ w3,
                                                   unsigned short* __restrict__ dst) {
    int which = blockIdx.x >> 10;
    int i = (blockIdx.x & 1023) * 256 + threadIdx.x;   // float4 index, 256K per matrix
    const float* src = which == 0 ? w0 : which == 1 ? w1 : which == 2 ? w2 : w3;
    unsigned short* d = dst + (size_t)which * 1024 * 1024;
    float4 v = ((const float4*)src)[i];
    ushort4 o;
    o.x = f2bf(v.x); o.y = f2bf(v.y); o.z = f2bf(v.z); o.w = f2bf(v.w);
    ((ushort4*)d)[i] = o;
}

// ---------------- 128x128 GEMM: C = A(MxK) * W(NxK)^T, 2-phase prefetch ----------------
// MODE 0: RoPE epilogue, write bf16 to (b,h,s,dk)
// MODE 1: write bf16 to (b,h,dk,s)   (transposed V)
// MODE 2: write fp32 to (m,n) d_out
template <int MODE>
__global__ __launch_bounds__(256) void gemm128(const unsigned short* __restrict__ A,
                                               const unsigned short* __restrict__ W,
                                               void* __restrict__ dst) {
    __shared__ __align__(16) unsigned short As[2][128 * 64];
    __shared__ __align__(16) unsigned short Bs[2][128 * 64];

    const int tid  = threadIdx.x;
    const int lane = tid & 63;
    const int wid  = tid >> 6;
    const int wm = wid >> 1, wn = wid & 1;
    const int l15 = lane & 15, lg = lane >> 4;

    const int tn = blockIdx.x & 7;   // N/128 = 8
    const int tm = blockIdx.x >> 3;
    const int m0 = tm * 128, n0 = tn * 128;

    f32x4 acc[4][4];
#pragma unroll
    for (int i = 0; i < 4; i++)
#pragma unroll
        for (int j = 0; j < 4; j++) acc[i][j] = f32x4{0.f, 0.f, 0.f, 0.f};

    // per-thread staging geometry (fixed across iterations)
    const int e0 = tid * 8;   // first of 4 chunks; +2048 per is

    auto STAGE = [&](int kk, int bufi) {
#pragma unroll
        for (int is = 0; is < 4; ++is) {
            int e = is * 2048 + e0;
            int row = e >> 6, col = e & 63;
            gload_lds16(A + (size_t)(m0 + row) * 1024 + kk + col, &As[bufi][e]);
            gload_lds16(W + (size_t)(n0 + row) * 1024 + kk + col, &Bs[bufi][e]);
        }
    };

    STAGE(0, 0);
    __syncthreads();

    for (int kk = 0; kk < 1024; kk += 64) {
        const int cur = (kk >> 6) & 1;
        if (kk + 64 < 1024) STAGE(kk + 64, cur ^ 1);   // issue-early
#pragma unroll
        for (int ks = 0; ks < 2; ++ks) {
            bf16x8 a[4], b[4];
#pragma unroll
            for (int f = 0; f < 4; f++) {
                a[f] = lds_frag(&As[cur][(wm * 64 + f * 16 + l15) * 64 + ks * 32 + lg * 8]);
                b[f] = lds_frag(&Bs[cur][(wn * 64 + f * 16 + l15) * 64 + ks * 32 + lg * 8]);
            }
#pragma unroll
            for (int i = 0; i < 4; i++)
#pragma unroll
                for (int j = 0; j < 4; j++)
                    acc[i][j] = __builtin_amdgcn_mfma_f32_16x16x32_bf16(a[i], b[j], acc[i][j], 0, 0, 0);
        }
        __syncthreads();   // drain-late: waits the prefetch + guards buffer reuse
    }

    // epilogue: lane holds C[m][n], m = m0+wm*64+i*16+lg*4+r, n = n0+wn*64+j*16+l15
    if (MODE == 2) {
        float* out = (float*)dst;
#pragma unroll
        for (int i = 0; i < 4; i++)
#pragma unroll
            for (int r = 0; r < 4; r++) {
                int m = m0 + wm * 64 + i * 16 + lg * 4 + r;
                float* orow = out + (size_t)m * 1024 + n0 + wn * 64 + l15;
#pragma unroll
                for (int j = 0; j < 4; j++) orow[j * 16] = acc[i][j][r];
            }
    } else if (MODE == 1) {
        unsigned short* out = (unsigned short*)dst;
#pragma unroll
        for (int i = 0; i < 4; i++)
#pragma unroll
            for (int r = 0; r < 4; r++) {
                int m = m0 + wm * 64 + i * 16 + lg * 4 + r;
                int b = m >> 11, s = m & 2047;
#pragma unroll
                for (int j = 0; j < 4; j++) {
                    int n = n0 + wn * 64 + j * 16 + l15;
                    int h = n >> 6, dk = n & 63;
                    out[((size_t)(b * NHEAD + h) * 64 + dk) * SEQ + s] = f2bf(acc[i][j][r]);
                }
            }
    } else {
        unsigned short* out = (unsigned short*)dst;
        const float L2T = 13.287712379549449f;   // log2(10000)
        float invf[4];
#pragma unroll
        for (int j = 0; j < 4; j++) {
            int idx = j * 16 + l15;          // n % 64
            int t = idx >> 1;
            invf[j] = exp2f(-((float)(2 * t) * (1.0f / 64.0f)) * L2T);
        }
        const int par = l15 & 1;
#pragma unroll
        for (int i = 0; i < 4; i++)
#pragma unroll
            for (int r = 0; r < 4; r++) {
                int m = m0 + wm * 64 + i * 16 + lg * 4 + r;
                int b = m >> 11, s = m & 2047;
                float fs = (float)s;
#pragma unroll
                for (int j = 0; j < 4; j++) {
                    float v = acc[i][j][r];
                    float other = __shfl_xor(v, 1);
                    float sn, cs;
                    __sincosf(fs * invf[j], &sn, &cs);
                    float y = par ? fmaf(v, cs, other * sn) : fmaf(v, cs, -other * sn);
                    int n = n0 + wn * 64 + j * 16 + l15;
                    int h = n >> 6, dk = n & 63;
                    out[((size_t)(b * NHEAD + h) * SEQ + s) * 64 + dk] = f2bf(y);
                }
            }
    }
}

// ---------------- causal flash attention ----------------
// Q,K in (bh, s, dk); V in (bh, dk, s). Out (b,s,dmodel) bf16.
// LDS tiles XOR-swizzled: LDS[row][chunk c] holds global [row][c ^ (row&7)] (16B chunks).
// Achieved by pre-swizzling the global source (gload_lds dest stays linear, rule 21).
__global__ __launch_bounds__(256) void flash_attn(const unsigned short* __restrict__ Qw,
                                                  const unsigned short* __restrict__ Kw,
                                                  const unsigned short* __restrict__ Vw,
                                                  unsigned short* __restrict__ Ow) {
    __shared__ __align__(16) unsigned short Qs[64 * 64];
    __shared__ __align__(16) unsigned short Ks[2][64 * 64];
    __shared__ __align__(16) unsigned short Vs[2][64 * 64];   // [dk][kv]
    __shared__ __align__(16) unsigned short Ps[64 * 72];      // padded rows (2-way max)

    const int tid  = threadIdx.x;
    const int lane = tid & 63;
    const int w    = tid >> 6;
    const int l15 = lane & 15, lg = lane >> 4;

    // XCD-aware swizzle (2048 % 8 == 0 -> simple form), bh-major, heavy-qb-first
    const int logical = (blockIdx.x & 7) * 256 + (blockIdx.x >> 3);
    const int bh = logical >> 5;
    const int qb = 31 - (logical & 31);

    const unsigned short* Qbase = Qw + (size_t)bh * (SEQ * 64) + qb * (64 * 64);
    const unsigned short* Kbh   = Kw + (size_t)bh * (SEQ * 64);
    const unsigned short* Vbh   = Vw + (size_t)bh * (64 * SEQ);

    // stage Q (swizzled source)
#pragma unroll
    for (int is = 0; is < 2; ++is) {
        int e = (is * 256 + tid) * 8;
        int row = e >> 6, c = (e >> 3) & 7;
        gload_lds16(Qbase + row * 64 + ((c ^ (row & 7)) << 3), &Qs[e]);
    }

    auto STAGE = [&](int kt2, int bufi) {
#pragma unroll
        for (int is = 0; is < 2; ++is) {
            int e = (is * 256 + tid) * 8;
            int row = e >> 6, c = (e >> 3) & 7;
            int sc = (c ^ (row & 7)) << 3;
            gload_lds16(Kbh + (size_t)kt2 * 4096 + row * 64 + sc, &Ks[bufi][e]);
            gload_lds16(Vbh + (size_t)row * SEQ + kt2 * 64 + sc, &Vs[bufi][e]);
        }
    };

    STAGE(0, 0);

    f32x4 oacc[4];
#pragma unroll
    for (int f = 0; f < 4; f++) oacc[f] = f32x4{0.f, 0.f, 0.f, 0.f};
    float mrun[4], lrun[4];
#pragma unroll
    for (int r = 0; r < 4; r++) { mrun[r] = -3.0e38f; lrun[r] = 0.f; }

    const int qrow0 = w * 16;
    const int l7 = l15 & 7;

    __syncthreads();   // Q + first K/V tile staged (implicit vmcnt(0))

    for (int kt = 0; kt <= qb; ++kt) {
        const int cur = kt & 1;
        if (kt < qb) STAGE(kt + 1, cur ^ 1);   // issue-early; drained by end-of-iter barrier

        // S = Q K^T   (swizzled reads)
        f32x4 sacc[4];
#pragma unroll
        for (int f = 0; f < 4; f++) sacc[f] = f32x4{0.f, 0.f, 0.f, 0.f};
#pragma unroll
        for (int ks = 0; ks < 2; ++ks) {
            bf16x8 aq = lds_frag(&Qs[(qrow0 + l15) * 64 + (((ks * 4 + lg) ^ l7) << 3)]);
#pragma unroll
            for (int f = 0; f < 4; f++) {
                bf16x8 bk = lds_frag(&Ks[cur][(f * 16 + l15) * 64 + (((ks * 4 + lg) ^ l7) << 3)]);
                sacc[f] = __builtin_amdgcn_mfma_f32_16x16x32_bf16(aq, bk, sacc[f], 0, 0, 0);
            }
        }

        // scale + causal mask (diag tile only)
        if (kt == qb) {
#pragma unroll
            for (int f = 0; f < 4; f++) {
                int kvl = f * 16 + l15;
#pragma unroll
                for (int r = 0; r < 4; r++) {
                    int ql = qrow0 + lg * 4 + r;
                    float v = sacc[f][r] * 0.125f;
                    sacc[f][r] = (kvl > ql) ? -3.0e38f : v;
                }
            }
        } else {
#pragma unroll
            for (int f = 0; f < 4; f++)
#pragma unroll
                for (int r = 0; r < 4; r++) sacc[f][r] *= 0.125f;
        }

        // online softmax; rows of reg r live in a fixed 16-lane group -> butterfly 1/2/4/8
        float sc[4];
#pragma unroll
        for (int r = 0; r < 4; r++) {
            float tmax = fmaxf(fmaxf(sacc[0][r], sacc[1][r]), fmaxf(sacc[2][r], sacc[3][r]));
            tmax = fmaxf(tmax, __shfl_xor(tmax, 1));
            tmax = fmaxf(tmax, __shfl_xor(tmax, 2));
            tmax = fmaxf(tmax, __shfl_xor(tmax, 4));
            tmax = fmaxf(tmax, __shfl_xor(tmax, 8));
            float mnew = fmaxf(mrun[r], tmax);
            sc[r] = __expf(mrun[r] - mnew);
            mrun[r] = mnew;
            float lsum = 0.f;
#pragma unroll
            for (int f = 0; f < 4; f++) {
                float e = __expf(sacc[f][r] - mnew);
                sacc[f][r] = e;
                lsum += e;
            }
            lsum += __shfl_xor(lsum, 1);
            lsum += __shfl_xor(lsum, 2);
            lsum += __shfl_xor(lsum, 4);
            lsum += __shfl_xor(lsum, 8);
            lrun[r] = lrun[r] * sc[r] + lsum;
        }
#pragma unroll
        for (int f = 0; f < 4; f++)
#pragma unroll
            for (int r = 0; r < 4; r++) oacc[f][r] *= sc[r];

        // P -> LDS (each wave writes/reads only its own 16 q-rows; no barrier needed)
#pragma unroll
        for (int f = 0; f < 4; f++)
#pragma unroll
            for (int r = 0; r < 4; r++)
                Ps[(qrow0 + lg * 4 + r) * 72 + f * 16 + l15] = f2bf(sacc[f][r]);

        // O += P V   (V reads swizzled)
#pragma unroll
        for (int ks = 0; ks < 2; ++ks) {
            bf16x8 pa = lds_frag(&Ps[(qrow0 + l15) * 72 + ks * 32 + lg * 8]);
#pragma unroll
            for (int f = 0; f < 4; f++) {
                bf16x8 vb = lds_frag(&Vs[cur][(f * 16 + l15) * 64 + (((ks * 4 + lg) ^ l7) << 3)]);
                oacc[f] = __builtin_amdgcn_mfma_f32_16x16x32_bf16(pa, vb, oacc[f], 0, 0, 0);
            }
        }
        __syncthreads();   // drain-late (vmcnt(0) for prefetch) + buffer-reuse guard
    }

    const int b = bh >> 4, h = bh & 15;
#pragma unroll
    for (int r = 0; r < 4; r++) {
        int sg = qb * 64 + qrow0 + lg * 4 + r;
        float inv = 1.0f / lrun[r];
        unsigned short* orow = Ow + ((size_t)(b * SEQ + sg) * DMODEL) + h * 64 + l15;
#pragma unroll
        for (int f = 0; f < 4; f++) orow[f * 16] = f2bf(oacc[f][r] * inv);
    }
}

extern "C" void kernel_launch(void* const* d_in, const int* in_sizes, int n_in,
                              void* d_out, int out_size, void* d_ws, size_t ws_size,
                              hipStream_t stream) {
    const float* x  = (const float*)d_in[0];
    const float* wq = (const float*)d_in[1];
    const float* wk = (const float*)d_in[2];
    const float* wv = (const float*)d_in[3];
    const float* wo = (const float*)d_in[4];

    unsigned short* ws = (unsigned short*)d_ws;
    const size_t MEL = (size_t)8192 * 1024;   // 8M elements
    const size_t WEL = (size_t)1024 * 1024;   // 1M elements
    unsigned short* xb  = ws;
    unsigned short* wqb = xb + MEL;           // 4 weights contiguous
    unsigned short* wkb = wqb + WEL;
    unsigned short* wvb = wkb + WEL;
    unsigned short* wob = wvb + WEL;
    unsigned short* qw  = wob + WEL;
    unsigned short* kw  = qw + MEL;
    unsigned short* vw  = kw + MEL;
    unsigned short* ow  = vw + MEL;
    // total: 44M ushort = 88 MB of d_ws

    cvt_f32_bf16<<<8192, 256, 0, stream>>>(x, xb, (int)(MEL / 4));
    cvt_weights<<<4096, 256, 0, stream>>>(wq, wk, wv, wo, wqb);

    gemm128<0><<<512, 256, 0, stream>>>(xb, wqb, qw);   // Q + RoPE -> (b,h,s,dk)
    gemm128<0><<<512, 256, 0, stream>>>(xb, wkb, kw);   // K + RoPE -> (b,h,s,dk)
    gemm128<1><<<512, 256, 0, stream>>>(xb, wvb, vw);   // V -> (b,h,dk,s)

    flash_attn<<<4 * NHEAD * 32, 256, 0, stream>>>(qw, kw, vw, ow);

    gemm128<2><<<512, 256, 0, stream>>>(ow, wob, d_out);
}

// Round 4
// 198.985 us; speedup vs baseline: 2.0799x; 1.3227x over previous
//
#include <hip/hip_runtime.h>
#include <stdint.h>

#define NHEAD  16
#define SEQ    2048
#define DMODEL 1024
#define BATCH  4

typedef __attribute__((ext_vector_type(4))) float f32x4;
typedef __attribute__((ext_vector_type(8))) __bf16 bf16x8;
typedef __attribute__((ext_vector_type(8))) unsigned short u16x8;

__device__ __forceinline__ unsigned short f2bf(float f) {
    unsigned int u = __builtin_bit_cast(unsigned int, f);
    u += 0x7FFFu + ((u >> 16) & 1u);   // RNE
    return (unsigned short)(u >> 16);
}

__device__ __forceinline__ unsigned int cvt_pk_bf16(float lo, float hi) {
    unsigned int r;
    asm("v_cvt_pk_bf16_f32 %0, %1, %2" : "=v"(r) : "v"(lo), "v"(hi));
    return r;
}

// async global->LDS, 16B per lane. LDS dest must be wave-uniform base + lane*16.
__device__ __forceinline__ void gload_lds16(const void* g, void* l) {
    __builtin_amdgcn_global_load_lds(
        (const __attribute__((address_space(1))) unsigned int*)(uintptr_t)g,
        (__attribute__((address_space(3))) unsigned int*)(uintptr_t)l,
        16, 0, 0);
}

__device__ __forceinline__ bf16x8 lds_frag(const unsigned short* p) {
    return __builtin_bit_cast(bf16x8, *(const u16x8*)p);
}

// ---------------- fp32 -> bf16 conversion ----------------
__global__ __launch_bounds__(256) void cvt_f32_bf16(const float* __restrict__ src,
                                                    unsigned short* __restrict__ dst, int n4) {
    int i = blockIdx.x * 256 + threadIdx.x;
    if (i < n4) {
        float4 v = ((const float4*)src)[i];
        ushort4 o;
        o.x = f2bf(v.x); o.y = f2bf(v.y); o.z = f2bf(v.z); o.w = f2bf(v.w);
        ((ushort4*)dst)[i] = o;
    }
}

__global__ __launch_bounds__(256) void cvt_weights(const float* __restrict__ w0,
                                                   const float* __restrict__ w1,
                                                   const float* __restrict__ w2,
                                                   const float* __restrict__ w3,
                                                   unsigned short* __restrict__ dst) {
    int which = blockIdx.x >> 10;
    int i = (blockIdx.x & 1023) * 256 + threadIdx.x;
    const float* src = which == 0 ? w0 : which == 1 ? w1 : which == 2 ? w2 : w3;
    unsigned short* d = dst + (size_t)which * 1024 * 1024;
    float4 v = ((const float4*)src)[i];
    ushort4 o;
    o.x = f2bf(v.x); o.y = f2bf(v.y); o.z = f2bf(v.z); o.w = f2bf(v.w);
    ((ushort4*)d)[i] = o;
}

// ---------------- fused QKV GEMM: [Q|K|V] = X(8192x1024) * Wcat(3072x1024)^T ----------------
// grid (24, 64): x = n-tile (0-7 Q, 8-15 K, 16-23 V), y = m-tile
__global__ __launch_bounds__(256) void gemm_qkv(const unsigned short* __restrict__ A,
                                                const unsigned short* __restrict__ Wc,
                                                unsigned short* __restrict__ qw,
                                                unsigned short* __restrict__ kw,
                                                unsigned short* __restrict__ vw) {
    __shared__ __align__(16) unsigned short As[2][128 * 64];
    __shared__ __align__(16) unsigned short Bs[2][128 * 64];

    const int tid  = threadIdx.x;
    const int lane = tid & 63;
    const int wid  = tid >> 6;
    const int wm = wid >> 1, wn = wid & 1;
    const int l15 = lane & 15, lg = lane >> 4;

    const int tn = blockIdx.x;
    const int m0 = blockIdx.y * 128, n0 = tn * 128;

    f32x4 acc[4][4];
#pragma unroll
    for (int i = 0; i < 4; i++)
#pragma unroll
        for (int j = 0; j < 4; j++) acc[i][j] = f32x4{0.f, 0.f, 0.f, 0.f};

    const int e0 = tid * 8;
    auto STAGE = [&](int kk, int bufi) {
#pragma unroll
        for (int is = 0; is < 4; ++is) {
            int e = is * 2048 + e0;
            int row = e >> 6, col = e & 63;
            gload_lds16(A  + (size_t)(m0 + row) * 1024 + kk + col, &As[bufi][e]);
            gload_lds16(Wc + (size_t)(n0 + row) * 1024 + kk + col, &Bs[bufi][e]);
        }
    };

    STAGE(0, 0);
    __syncthreads();

    for (int kk = 0; kk < 1024; kk += 64) {
        const int cur = (kk >> 6) & 1;
        if (kk + 64 < 1024) STAGE(kk + 64, cur ^ 1);
#pragma unroll
        for (int ks = 0; ks < 2; ++ks) {
            bf16x8 a[4], b[4];
#pragma unroll
            for (int f = 0; f < 4; f++) {
                a[f] = lds_frag(&As[cur][(wm * 64 + f * 16 + l15) * 64 + ks * 32 + lg * 8]);
                b[f] = lds_frag(&Bs[cur][(wn * 64 + f * 16 + l15) * 64 + ks * 32 + lg * 8]);
            }
#pragma unroll
            for (int i = 0; i < 4; i++)
#pragma unroll
                for (int j = 0; j < 4; j++)
                    acc[i][j] = __builtin_amdgcn_mfma_f32_16x16x32_bf16(a[i], b[j], acc[i][j], 0, 0, 0);
        }
        __syncthreads();
    }

    if (tn >= 16) {   // V -> (b,h,dk,s) transposed
        unsigned short* out = vw;
#pragma unroll
        for (int i = 0; i < 4; i++)
#pragma unroll
            for (int r = 0; r < 4; r++) {
                int m = m0 + wm * 64 + i * 16 + lg * 4 + r;
                int b = m >> 11, s = m & 2047;
#pragma unroll
                for (int j = 0; j < 4; j++) {
                    int n = n0 + wn * 64 + j * 16 + l15;
                    int h = (n >> 6) & 15, dk = n & 63;
                    out[((size_t)(b * NHEAD + h) * 64 + dk) * SEQ + s] = f2bf(acc[i][j][r]);
                }
            }
    } else {          // Q or K with RoPE -> (b,h,s,dk)
        unsigned short* out = (tn < 8) ? qw : kw;
        const float L2T = 13.287712379549449f;   // log2(10000)
        float invf[4];
#pragma unroll
        for (int j = 0; j < 4; j++) {
            int idx = j * 16 + l15;          // n % 64
            int t = idx >> 1;
            invf[j] = exp2f(-((float)(2 * t) * (1.0f / 64.0f)) * L2T);
        }
        const int par = l15 & 1;
#pragma unroll
        for (int i = 0; i < 4; i++)
#pragma unroll
            for (int r = 0; r < 4; r++) {
                int m = m0 + wm * 64 + i * 16 + lg * 4 + r;
                int b = m >> 11, s = m & 2047;
                float fs = (float)s;
#pragma unroll
                for (int j = 0; j < 4; j++) {
                    float v = acc[i][j][r];
                    float other = __shfl_xor(v, 1);
                    float sn, cs;
                    __sincosf(fs * invf[j], &sn, &cs);
                    float y = par ? fmaf(v, cs, other * sn) : fmaf(v, cs, -other * sn);
                    int n = n0 + wn * 64 + j * 16 + l15;
                    int h = (n >> 6) & 15, dk = n & 63;
                    out[((size_t)(b * NHEAD + h) * SEQ + s) * 64 + dk] = f2bf(y);
                }
            }
    }
}

// ---------------- output GEMM: d_out = OW(8192x1024) * Wo(1024x1024)^T, fp32 out ----------------
__global__ __launch_bounds__(256) void gemm_out(const unsigned short* __restrict__ A,
                                                const unsigned short* __restrict__ W,
                                                float* __restrict__ out) {
    __shared__ __align__(16) unsigned short As[2][128 * 64];
    __shared__ __align__(16) unsigned short Bs[2][128 * 64];

    const int tid  = threadIdx.x;
    const int lane = tid & 63;
    const int wid  = tid >> 6;
    const int wm = wid >> 1, wn = wid & 1;
    const int l15 = lane & 15, lg = lane >> 4;

    const int tn = blockIdx.x & 7;
    const int tm = blockIdx.x >> 3;
    const int m0 = tm * 128, n0 = tn * 128;

    f32x4 acc[4][4];
#pragma unroll
    for (int i = 0; i < 4; i++)
#pragma unroll
        for (int j = 0; j < 4; j++) acc[i][j] = f32x4{0.f, 0.f, 0.f, 0.f};

    const int e0 = tid * 8;
    auto STAGE = [&](int kk, int bufi) {
#pragma unroll
        for (int is = 0; is < 4; ++is) {
            int e = is * 2048 + e0;
            int row = e >> 6, col = e & 63;
            gload_lds16(A + (size_t)(m0 + row) * 1024 + kk + col, &As[bufi][e]);
            gload_lds16(W + (size_t)(n0 + row) * 1024 + kk + col, &Bs[bufi][e]);
        }
    };

    STAGE(0, 0);
    __syncthreads();

    for (int kk = 0; kk < 1024; kk += 64) {
        const int cur = (kk >> 6) & 1;
        if (kk + 64 < 1024) STAGE(kk + 64, cur ^ 1);
#pragma unroll
        for (int ks = 0; ks < 2; ++ks) {
            bf16x8 a[4], b[4];
#pragma unroll
            for (int f = 0; f < 4; f++) {
                a[f] = lds_frag(&As[cur][(wm * 64 + f * 16 + l15) * 64 + ks * 32 + lg * 8]);
                b[f] = lds_frag(&Bs[cur][(wn * 64 + f * 16 + l15) * 64 + ks * 32 + lg * 8]);
            }
#pragma unroll
            for (int i = 0; i < 4; i++)
#pragma unroll
                for (int j = 0; j < 4; j++)
                    acc[i][j] = __builtin_amdgcn_mfma_f32_16x16x32_bf16(a[i], b[j], acc[i][j], 0, 0, 0);
        }
        __syncthreads();
    }

#pragma unroll
    for (int i = 0; i < 4; i++)
#pragma unroll
        for (int r = 0; r < 4; r++) {
            int m = m0 + wm * 64 + i * 16 + lg * 4 + r;
            float* orow = out + (size_t)m * 1024 + n0 + wn * 64 + l15;
#pragma unroll
            for (int j = 0; j < 4; j++) orow[j * 16] = acc[i][j][r];
        }
}

// ---------------- causal flash attention (swapped-QK^T, in-lane softmax) ----------------
// Q,K in (bh, s, dk); V in (bh, dk, s). Out (b,s,dmodel) bf16.
// K/V/P LDS XOR-swizzled at 16B-chunk granularity: chunk c of row -> c ^ (row&7).
__global__ __launch_bounds__(256, 4) void flash_attn(const unsigned short* __restrict__ Qw,
                                                     const unsigned short* __restrict__ Kw,
                                                     const unsigned short* __restrict__ Vw,
                                                     unsigned short* __restrict__ Ow) {
    __shared__ __align__(16) unsigned short Ks[2][64 * 64];
    __shared__ __align__(16) unsigned short Vs[2][64 * 64];   // [dk][kv]
    __shared__ __align__(16) unsigned short Ps[64 * 64];      // [q][kv], swizzled
    // total LDS = 40960 B -> 4 blocks/CU

    const int tid  = threadIdx.x;
    const int lane = tid & 63;
    const int w    = tid >> 6;
    const int l15 = lane & 15, lg = lane >> 4;
    const int l7 = l15 & 7;

    // XCD-aware swizzle, bh-major, heavy-qb-first
    const int logical = (blockIdx.x & 7) * 256 + (blockIdx.x >> 3);
    const int bh = logical >> 5;
    const int qb = 31 - (logical & 31);

    const unsigned short* Kbh = Kw + (size_t)bh * (SEQ * 64);
    const unsigned short* Vbh = Vw + (size_t)bh * (64 * SEQ);

    const int qrow0 = w * 16;          // wave's q range within the 64-row block
    const int prow  = qrow0 + l15;     // this lane's softmax q (block-local)

    // Q fragments in registers (loop-invariant): q = prow, dk = ks*32 + lg*8 .. +7
    const unsigned short* Qrow = Qw + (size_t)bh * (SEQ * 64) + (size_t)(qb * 64 + prow) * 64;
    bf16x8 qf[2];
    qf[0] = __builtin_bit_cast(bf16x8, *(const u16x8*)(Qrow + lg * 8));
    qf[1] = __builtin_bit_cast(bf16x8, *(const u16x8*)(Qrow + 32 + lg * 8));

    auto STAGE = [&](int kt2, int bufi) {
#pragma unroll
        for (int is = 0; is < 2; ++is) {
            int e = (is * 256 + tid) * 8;
            int row = e >> 6, c = (e >> 3) & 7;
            int sc = (c ^ (row & 7)) << 3;
            gload_lds16(Kbh + (size_t)kt2 * 4096 + row * 64 + sc, &Ks[bufi][e]);
            gload_lds16(Vbh + (size_t)row * SEQ + kt2 * 64 + sc, &Vs[bufi][e]);
        }
    };

    STAGE(0, 0);

    f32x4 oacc[4];   // oacc[f][r]: O[q=qrow0+4lg+r][dk=16f+l15]
#pragma unroll
    for (int f = 0; f < 4; f++) oacc[f] = f32x4{0.f, 0.f, 0.f, 0.f};
    float mrun = -3.0e38f, lrun = 0.f;   // for q = prow

    const float SC = 0.18033688011112042f;   // 1/8 * log2(e)

    __syncthreads();

    for (int kt = 0; kt <= qb; ++kt) {
        const int cur = kt & 1;
        if (kt < qb) STAGE(kt + 1, cur ^ 1);   // issue-early; drained by end-of-iter barrier

        // S^T tiles: st[f] = mfma(K_f, Q): lane holds S[kv=16f+4lg+r][q=prow]
        f32x4 st[4];
#pragma unroll
        for (int f = 0; f < 4; f++) st[f] = f32x4{0.f, 0.f, 0.f, 0.f};
        __builtin_amdgcn_s_setprio(1);
#pragma unroll
        for (int ks = 0; ks < 2; ++ks) {
#pragma unroll
            for (int f = 0; f < 4; f++) {
                bf16x8 kfrag = lds_frag(&Ks[cur][(f * 16 + l15) * 64 + (((ks * 4 + lg) ^ l7) << 3)]);
                st[f] = __builtin_amdgcn_mfma_f32_16x16x32_bf16(kfrag, qf[ks], st[f], 0, 0, 0);
            }
        }
        __builtin_amdgcn_s_setprio(0);

        // scale into log2 domain (+ causal mask on diag tile)
        if (kt == qb) {
#pragma unroll
            for (int f = 0; f < 4; f++)
#pragma unroll
                for (int r = 0; r < 4; r++) {
                    int kv = f * 16 + 4 * lg + r;
                    float v = st[f][r] * SC;
                    st[f][r] = (kv > prow) ? -3.0e38f : v;
                }
        } else {
#pragma unroll
            for (int f = 0; f < 4; f++)
#pragma unroll
                for (int r = 0; r < 4; r++) st[f][r] *= SC;
        }

        // per-q max: 15 in-lane + 2 shuffles
        float pm = fmaxf(fmaxf(fmaxf(st[0][0], st[0][1]), fmaxf(st[0][2], st[0][3])),
                         fmaxf(fmaxf(st[1][0], st[1][1]), fmaxf(st[1][2], st[1][3])));
        pm = fmaxf(pm, fmaxf(fmaxf(fmaxf(st[2][0], st[2][1]), fmaxf(st[2][2], st[2][3])),
                             fmaxf(fmaxf(st[3][0], st[3][1]), fmaxf(st[3][2], st[3][3]))));
        pm = fmaxf(pm, __shfl_xor(pm, 16));
        pm = fmaxf(pm, __shfl_xor(pm, 32));

        // defer-max (T13): only rescale when some row grew by > 8 (in log2 domain)
        if (!__all(pm - mrun <= 8.0f)) {
            float mnew = fmaxf(mrun, pm);
            float sc0 = exp2f(mrun - mnew);
            mrun = mnew;
            lrun *= sc0;
#pragma unroll
            for (int r = 0; r < 4; r++) {
                float so = __shfl(sc0, lg * 4 + r);   // sc for q = qrow0+4lg+r
#pragma unroll
                for (int f = 0; f < 4; f++) oacc[f][r] *= so;
            }
        }

        // exp2 + row-sum
        float lsum = 0.f;
#pragma unroll
        for (int f = 0; f < 4; f++)
#pragma unroll
            for (int r = 0; r < 4; r++) {
                float e = exp2f(st[f][r] - mrun);
                st[f][r] = e;
                lsum += e;
            }
        lsum += __shfl_xor(lsum, 16);
        lsum += __shfl_xor(lsum, 32);
        lrun += lsum;

        // P -> Ps (bf16, packed b64 writes, swizzled); row = prow, kv = 16f+4lg+{0..3}
        {
            unsigned short* pbase = &Ps[prow * 64];
            const int halfoff = (lg & 1) << 2;
            const int cbase = lg >> 1;
#pragma unroll
            for (int f = 0; f < 4; f++) {
                uint2 pw;
                pw.x = cvt_pk_bf16(st[f][0], st[f][1]);
                pw.y = cvt_pk_bf16(st[f][2], st[f][3]);
                *(uint2*)(pbase + (((2 * f + cbase) ^ l7) << 3) + halfoff) = pw;
            }
        }

        // O += P V  (A = P rows from Ps, B = V^T rows from Vs)
        __builtin_amdgcn_s_setprio(1);
#pragma unroll
        for (int ks = 0; ks < 2; ++ks) {
            bf16x8 pa = lds_frag(&Ps[prow * 64 + (((ks * 4 + lg) ^ l7) << 3)]);
#pragma unroll
            for (int f = 0; f < 4; f++) {
                bf16x8 vb = lds_frag(&Vs[cur][(f * 16 + l15) * 64 + (((ks * 4 + lg) ^ l7) << 3)]);
                oacc[f] = __builtin_amdgcn_mfma_f32_16x16x32_bf16(pa, vb, oacc[f], 0, 0, 0);
            }
        }
        __builtin_amdgcn_s_setprio(0);
        __syncthreads();   // drains prefetch (vmcnt) + guards K/V buffer reuse
    }

    const int b = bh >> 4, h = bh & 15;
#pragma unroll
    for (int r = 0; r < 4; r++) {
        float lr = __shfl(lrun, lg * 4 + r);   // l for q = qrow0+4lg+r
        float inv = 1.0f / lr;
        int sg = qb * 64 + qrow0 + lg * 4 + r;
        unsigned short* orow = Ow + ((size_t)(b * SEQ + sg) * DMODEL) + h * 64 + l15;
#pragma unroll
        for (int f = 0; f < 4; f++) orow[f * 16] = f2bf(oacc[f][r] * inv);
    }
}

extern "C" void kernel_launch(void* const* d_in, const int* in_sizes, int n_in,
                              void* d_out, int out_size, void* d_ws, size_t ws_size,
                              hipStream_t stream) {
    const float* x  = (const float*)d_in[0];
    const float* wq = (const float*)d_in[1];
    const float* wk = (const float*)d_in[2];
    const float* wv = (const float*)d_in[3];
    const float* wo = (const float*)d_in[4];

    unsigned short* ws = (unsigned short*)d_ws;
    const size_t MEL = (size_t)8192 * 1024;   // 8M elements
    const size_t WEL = (size_t)1024 * 1024;   // 1M elements
    unsigned short* xb  = ws;
    unsigned short* wqb = xb + MEL;           // 4 weights contiguous: wq|wk|wv|wo
    unsigned short* wob = wqb + 3 * WEL;
    unsigned short* qw  = wob + WEL;
    unsigned short* kw  = qw + MEL;
    unsigned short* vw  = kw + MEL;
    unsigned short* ow  = vw + MEL;

    cvt_f32_bf16<<<8192, 256, 0, stream>>>(x, xb, (int)(MEL / 4));
    cvt_weights<<<4096, 256, 0, stream>>>(wq, wk, wv, wo, wqb);

    gemm_qkv<<<dim3(24, 64), 256, 0, stream>>>(xb, wqb, qw, kw, vw);

    flash_attn<<<4 * NHEAD * 32, 256, 0, stream>>>(qw, kw, vw, ow);

    gemm_out<<<512, 256, 0, stream>>>(ow, wob, (float*)d_out);
}